// Round 3
// baseline (2081.388 us; speedup 1.0000x reference)
//
#include <hip/hip_runtime.h>
#include <stdint.h>

typedef unsigned short u16;
typedef __attribute__((ext_vector_type(8))) short s16x8;   // 8 x bf16 (4 VGPRs)
typedef __attribute__((ext_vector_type(4))) float f32x4;   // MFMA accumulator

__device__ __forceinline__ f32x4 mfma16x16(s16x8 a, s16x8 b, f32x4 c) {
    return __builtin_amdgcn_mfma_f32_16x16x32_bf16(a, b, c, 0, 0, 0);
}

__device__ __forceinline__ u16 f2bf(float f) {
    union { float f; unsigned u; } c; c.f = f;
    unsigned u = c.u;
    return (u16)((u + 0x7FFFu + ((u >> 16) & 1u)) >> 16);   // RNE
}
__device__ __forceinline__ float bf2f(u16 b) {
    union { unsigned u; float f; } c; c.u = ((unsigned)b) << 16;
    return c.f;
}

// global -> LDS direct 16B load. LDS dest = wave-uniform base + lane*16.
// NOTE: proper addrspace casts (addrspacecast), not uintptr_t truncation.
__device__ __forceinline__ void gload16(const void* g, void* l) {
    auto gp = (const __attribute__((address_space(1))) unsigned int*)(g);
    auto lp = (__attribute__((address_space(3))) unsigned int*)(l);
    __builtin_amdgcn_global_load_lds(gp, lp, 16, 0, 0);
}

__device__ __forceinline__ void wave_sync() {
    __builtin_amdgcn_sched_barrier(0);
    asm volatile("s_waitcnt vmcnt(0) lgkmcnt(0)" ::: "memory");
    __builtin_amdgcn_sched_barrier(0);
    __builtin_amdgcn_s_barrier();
    __builtin_amdgcn_sched_barrier(0);
}

// ---------------------------------------------------------------------------
// dtype detect: scan 2M u16 of x for bf16-NaN/Inf exponent patterns.
// fp32 buffer -> ~4000 hits (random mantissa words); bf16 buffer -> 0.
// ---------------------------------------------------------------------------
__global__ void detect_dtype(const u16* __restrict__ x, int* __restrict__ flag)
{
    __shared__ int cnt;
    if (threadIdx.x == 0) cnt = 0;
    __syncthreads();
    int c = 0;
    for (int i = threadIdx.x; i < (1 << 21); i += 256)
        if ((x[i] & 0x7F80u) == 0x7F80u) c++;
    atomicAdd(&cnt, c);
    __syncthreads();
    if (threadIdx.x == 0) *flag = (cnt > 8) ? 1 : 0;   // 1 = fp32 inputs
}

// ---------------------------------------------------------------------------
// convert to bf16 (or pass-through copy when already bf16). n % 8 == 0.
// ---------------------------------------------------------------------------
__global__ __launch_bounds__(256) void convert_to_bf16(
    const void* __restrict__ src, u16* __restrict__ dst, long n,
    const int* __restrict__ flag)
{
    const int f = *flag;
    const long stride = (long)gridDim.x * 256 * 8;
    for (long i = ((long)blockIdx.x * 256 + threadIdx.x) * 8; i < n; i += stride) {
        if (f) {
            const float* s = (const float*)src + i;
            const float4 a = *(const float4*)(s);
            const float4 b = *(const float4*)(s + 4);
            u16 o[8] = { f2bf(a.x), f2bf(a.y), f2bf(a.z), f2bf(a.w),
                         f2bf(b.x), f2bf(b.y), f2bf(b.z), f2bf(b.w) };
            *(s16x8*)(dst + i) = *(const s16x8*)o;
        } else {
            *(s16x8*)(dst + i) = *(const s16x8*)((const u16*)src + i);
        }
    }
}

__global__ __launch_bounds__(256) void fill_sentinel(u16* __restrict__ o, long n)
{
    const long stride = (long)gridDim.x * 256;
    for (long i = (long)blockIdx.x * 256 + threadIdx.x; i < n; i += stride)
        o[i] = 0x3F80u;   // bf16 1.0 sentinel: ws_size too small
}

// ---------------------------------------------------------------------------
// Transpose (bf16): in [R][C] -> out [C][R]
// ---------------------------------------------------------------------------
__global__ __launch_bounds__(256) void transpose16(
    const u16* __restrict__ in, u16* __restrict__ out, int R, int C)
{
    __shared__ u16 t[32][33];
    const int c0 = blockIdx.x * 32, r0 = blockIdx.y * 32;
    const int tx = threadIdx.x & 31, ty = threadIdx.x >> 5;
#pragma unroll
    for (int i = 0; i < 32; i += 8)
        t[ty + i][tx] = in[(long)(r0 + ty + i) * C + c0 + tx];
    __syncthreads();
#pragma unroll
    for (int i = 0; i < 32; i += 8)
        out[(long)(c0 + ty + i) * R + r0 + tx] = t[tx][ty + i];
}

// ---------------------------------------------------------------------------
// C[M][N] = A[M][K] @ BT[N][K]^T + bias[N]   (bf16 in, fp32 accum)
// 128x128 tile, BK=64, 4 waves (2x2 of 64x64), 16x16x32 MFMA.
// Output: bf16 (fp32f==nullptr or *fp32f==0) or fp32 (*fp32f==1).
// ---------------------------------------------------------------------------
__global__ __launch_bounds__(256) void gemm_bt_bias(
    const u16* __restrict__ A, const u16* __restrict__ BT,
    const u16* __restrict__ bias, void* __restrict__ Cout,
    int M, int N, int K, const int* __restrict__ fp32f)
{
    __shared__ u16 As[128 * 64];
    __shared__ u16 Bs[128 * 64];
    const int tid  = threadIdx.x;
    const int lane = tid & 63;
    const int wid  = tid >> 6;
    const int rr   = lane & 15, g = lane >> 4;
    const int wm   = (wid >> 1) << 6;
    const int wn   = (wid & 1) << 6;
    const long m0  = (long)blockIdx.y * 128;
    const long n0  = (long)blockIdx.x * 128;
    const int srow   = tid >> 3;               // 0..31
    const int schunk = (tid & 7) ^ (srow & 7); // pre-swizzled 16B-chunk index

    f32x4 acc[4][4] = {};

    for (int k0 = 0; k0 < K; k0 += 64) {
#pragma unroll
        for (int q = 0; q < 4; ++q) {
            const int row = q * 32 + srow;
            gload16(A  + (m0 + row) * K + k0 + schunk * 8,
                    (char*)As + q * 4096 + wid * 1024);
            gload16(BT + (n0 + row) * K + k0 + schunk * 8,
                    (char*)Bs + q * 4096 + wid * 1024);
        }
        __syncthreads();
#pragma unroll
        for (int kk = 0; kk < 2; ++kk) {
            s16x8 af[4], bfr[4];
#pragma unroll
            for (int i = 0; i < 4; ++i) {
                const int rowa = wm + i * 16 + rr;
                af[i] = *(const s16x8*)((const char*)As + rowa * 128 +
                         ((kk * 64 + g * 16) ^ ((rowa & 7) << 4)));
                const int rowb = wn + i * 16 + rr;
                bfr[i] = *(const s16x8*)((const char*)Bs + rowb * 128 +
                         ((kk * 64 + g * 16) ^ ((rowb & 7) << 4)));
            }
#pragma unroll
            for (int i = 0; i < 4; ++i)
#pragma unroll
                for (int j = 0; j < 4; ++j)
                    acc[i][j] = mfma16x16(af[i], bfr[j], acc[i][j]);
        }
        __syncthreads();
    }

    const int f = fp32f ? *fp32f : 0;
#pragma unroll
    for (int j = 0; j < 4; ++j) {
        const long col = n0 + wn + j * 16 + rr;
        const float bv = bf2f(bias[col]);
#pragma unroll
        for (int i = 0; i < 4; ++i)
#pragma unroll
            for (int r = 0; r < 4; ++r) {
                const long rowg = m0 + wm + i * 16 + g * 4 + r;
                const float v = acc[i][j][r] + bv;
                if (f) ((float*)Cout)[rowg * N + col] = v;
                else   ((u16*)Cout)[rowg * N + col] = f2bf(v);
            }
    }
}

// ---------------------------------------------------------------------------
// Factored attention: one wave per (b, h, p). Attention over NB=64 blocks.
// qkv row = b*8192 + n*128 + p, col = c*1024 + h*64 + d   (bf16)
// T = K @ Q^T (= S^T): both operands row-loads from global into registers.
// ---------------------------------------------------------------------------
__global__ __launch_bounds__(64) void attn_blocks(
    const u16* __restrict__ qkv, u16* __restrict__ o)
{
    __shared__ u16 Vlds[64 * 64];   // [k=64][d=64], rows XOR-swizzled by chunk
    __shared__ u16 Plds[64 * 72];   // [n=64][m=64 + pad 8]
    const int bid = blockIdx.x;
    const int b = bid >> 11;
    const int h = (bid >> 7) & 15;
    const int p = bid & 127;
    const int lane = threadIdx.x;
    const int rr = lane & 15, g = lane >> 4;
    const long NSTR = 128L * 3072;
    const long base = ((long)b * 8192 + p) * 3072 + h * 64;

    {   // stage V (c=2) into LDS, source pre-swizzled
        const int vrow = lane >> 3;
        const int vchunk = (lane & 7) ^ (vrow & 7);
#pragma unroll
        for (int q = 0; q < 8; ++q)
            gload16(qkv + base + (long)(q * 8 + vrow) * NSTR + 2048 + vchunk * 8,
                    (char*)Vlds + q * 1024);
    }

    s16x8 kf[4][2], qf[4][2];
#pragma unroll
    for (int t = 0; t < 4; ++t)
#pragma unroll
        for (int ks = 0; ks < 2; ++ks) {
            const long roff = base + (long)(t * 16 + rr) * NSTR + ks * 32 + g * 8;
            kf[t][ks] = *(const s16x8*)(qkv + roff + 1024);
            qf[t][ks] = *(const s16x8*)(qkv + roff);
        }

    f32x4 T[4][4] = {};
#pragma unroll
    for (int ks = 0; ks < 2; ++ks)
#pragma unroll
        for (int i = 0; i < 4; ++i)
#pragma unroll
            for (int jn = 0; jn < 4; ++jn)
                T[i][jn] = mfma16x16(kf[i][ks], qf[jn][ks], T[i][jn]);

    const float scale = 0.125f;
#pragma unroll
    for (int jn = 0; jn < 4; ++jn) {
        const int n = jn * 16 + rr;
        float pv[16];
        float mx = -3e38f;
#pragma unroll
        for (int i = 0; i < 4; ++i)
#pragma unroll
            for (int r = 0; r < 4; ++r) {
                const int m = i * 16 + g * 4 + r;
                const float s = (m <= n) ? T[i][jn][r] * scale : -3e38f;
                pv[i * 4 + r] = s;
                mx = fmaxf(mx, s);
            }
        mx = fmaxf(mx, __shfl_xor(mx, 16));
        mx = fmaxf(mx, __shfl_xor(mx, 32));
        float sum = 0.f;
#pragma unroll
        for (int t = 0; t < 16; ++t) {
            const float e = (pv[t] > -1e30f) ? __expf(pv[t] - mx) : 0.f;
            pv[t] = e;
            sum += e;
        }
        sum += __shfl_xor(sum, 16);
        sum += __shfl_xor(sum, 32);
        const float inv = 1.f / sum;
#pragma unroll
        for (int i = 0; i < 4; ++i)
#pragma unroll
            for (int rp = 0; rp < 2; ++rp) {
                const int m = i * 16 + g * 4 + rp * 2;
                const unsigned lo = f2bf(pv[i * 4 + rp * 2] * inv);
                const unsigned hi = f2bf(pv[i * 4 + rp * 2 + 1] * inv);
                *(unsigned*)((char*)Plds + n * 144 + m * 2) = lo | (hi << 16);
            }
    }

    wave_sync();   // drain V LDS-DMA (vmcnt) + P ds_writes (lgkmcnt)

    f32x4 O[4][4] = {};
#pragma unroll
    for (int ks = 0; ks < 2; ++ks) {
        s16x8 pa[4];
#pragma unroll
        for (int in = 0; in < 4; ++in)
            pa[in] = *(const s16x8*)((const char*)Plds +
                      (in * 16 + rr) * 144 + ks * 64 + g * 16);
#pragma unroll
        for (int jd = 0; jd < 4; ++jd) {
            s16x8 vb;
#pragma unroll
            for (int j = 0; j < 8; ++j) {
                const int k = ks * 32 + g * 8 + j;
                const int byte = (k * 128 + (jd * 16 + rr) * 2) ^ ((k & 7) << 4);
                vb[j] = *(const short*)((const char*)Vlds + byte);
            }
#pragma unroll
            for (int in = 0; in < 4; ++in)
                O[in][jd] = mfma16x16(pa[in], vb, O[in][jd]);
        }
    }

    const long obase = ((long)b * 8192 + p) * 1024 + h * 64;
#pragma unroll
    for (int in = 0; in < 4; ++in)
#pragma unroll
        for (int jd = 0; jd < 4; ++jd)
#pragma unroll
            for (int r = 0; r < 4; ++r) {
                const long n = in * 16 + g * 4 + r;
                const long d = jd * 16 + rr;
                o[obase + n * (128L * 1024) + d] = f2bf(O[in][jd][r]);
            }
}

// ---------------------------------------------------------------------------
extern "C" void kernel_launch(void* const* d_in, const int* in_sizes, int n_in,
                              void* d_out, int out_size, void* d_ws, size_t ws_size,
                              hipStream_t stream) {
    char* ws = (char*)d_ws;
    // ws layout (bytes, all 256-aligned)
    int*  flag  = (int*)(ws + 0);
    u16*  xb    = (u16*)(ws + 256);              //  33,554,432
    u16*  qkv   = (u16*)(ws + 33554688L);        // 100,663,296
    u16*  ob    = (u16*)(ws + 134217984L);       //  33,554,432
    u16*  Wq_c  = (u16*)(ws + 167772416L);       //   6,291,456
    u16*  WqkvT = (u16*)(ws + 174063872L);       //   6,291,456
    u16*  Wo_c  = (u16*)(ws + 180355328L);       //   2,097,152
    u16*  WoutT = (u16*)(ws + 182452480L);       //   2,097,152
    u16*  bq_c  = (u16*)(ws + 184549632L);       //       6,144
    u16*  bo_c  = (u16*)(ws + 184555776L);       //       2,048
    const size_t NEEDED = 184557824UL;

    if (ws_size < NEEDED) {   // diagnosable sentinel: all-1.0 output
        fill_sentinel<<<2048, 256, 0, stream>>>((u16*)d_out, (long)out_size);
        return;
    }

    detect_dtype<<<1, 256, 0, stream>>>((const u16*)d_in[0], flag);

    convert_to_bf16<<<4096, 256, 0, stream>>>(d_in[0], xb,   16777216L, flag);
    convert_to_bf16<<<1536, 256, 0, stream>>>(d_in[1], Wq_c,  3145728L, flag);
    convert_to_bf16<<< 512, 256, 0, stream>>>(d_in[3], Wo_c,  1048576L, flag);
    convert_to_bf16<<<   2, 256, 0, stream>>>(d_in[2], bq_c,     3072L, flag);
    convert_to_bf16<<<   1, 256, 0, stream>>>(d_in[4], bo_c,     1024L, flag);

    transpose16<<<dim3(96, 32), 256, 0, stream>>>(Wq_c, WqkvT, 1024, 3072);
    transpose16<<<dim3(32, 32), 256, 0, stream>>>(Wo_c, WoutT, 1024, 1024);

    // qkv = x @ Wqkv + bqkv   (M=16384, N=3072, K=1024) -> bf16 ws
    gemm_bt_bias<<<dim3(24, 128), 256, 0, stream>>>(xb, WqkvT, bq_c, qkv,
                                                    16384, 3072, 1024, nullptr);
    // factored attention over blocks
    attn_blocks<<<4096, 64, 0, stream>>>(qkv, ob);

    // out = o @ Wout + bout   (M=16384, N=1024, K=1024) -> d_out per flag
    gemm_bt_bias<<<dim3(8, 128), 256, 0, stream>>>(ob, WoutT, bo_c, d_out,
                                                   16384, 1024, 1024, flag);
}

// Round 4
// 240.692 us; speedup vs baseline: 8.6475x; 8.6475x over previous
//
#include <hip/hip_runtime.h>
#include <stdint.h>

typedef unsigned short u16;
typedef __attribute__((ext_vector_type(8))) short s16x8;   // 8 x bf16 (4 VGPRs)
typedef __attribute__((ext_vector_type(4))) float f32x4;   // MFMA accumulator

__device__ __forceinline__ f32x4 mfma16x16(s16x8 a, s16x8 b, f32x4 c) {
    return __builtin_amdgcn_mfma_f32_16x16x32_bf16(a, b, c, 0, 0, 0);
}

__device__ __forceinline__ u16 f2bf(float f) {
    union { float f; unsigned u; } c; c.f = f;
    unsigned u = c.u;
    return (u16)((u + 0x7FFFu + ((u >> 16) & 1u)) >> 16);   // RNE
}

// global -> LDS direct 16B load. LDS dest = wave-uniform base + lane*16.
__device__ __forceinline__ void gload16(const void* g, void* l) {
    auto gp = (const __attribute__((address_space(1))) unsigned int*)(g);
    auto lp = (__attribute__((address_space(3))) unsigned int*)(l);
    __builtin_amdgcn_global_load_lds(gp, lp, 16, 0, 0);
}

// Explicit drain + barrier for the single-wave attention block (compiler
// elides s_barrier at blockDim==64; LDS-DMA completion rides on vmcnt).
__device__ __forceinline__ void wave_sync() {
    __builtin_amdgcn_sched_barrier(0);
    asm volatile("s_waitcnt vmcnt(0) lgkmcnt(0)" ::: "memory");
    __builtin_amdgcn_sched_barrier(0);
    __builtin_amdgcn_s_barrier();
    __builtin_amdgcn_sched_barrier(0);
}

// ---------------------------------------------------------------------------
// x: fp32 -> bf16, vectorized, grid-stride. n % 8 == 0.
// ---------------------------------------------------------------------------
__global__ __launch_bounds__(256) void convert_x(
    const float* __restrict__ src, u16* __restrict__ dst, long n)
{
    const long stride = (long)gridDim.x * 256 * 8;
    for (long i = ((long)blockIdx.x * 256 + threadIdx.x) * 8; i < n; i += stride) {
        const float4 a = *(const float4*)(src + i);
        const float4 b = *(const float4*)(src + i + 4);
        u16 o[8] = { f2bf(a.x), f2bf(a.y), f2bf(a.z), f2bf(a.w),
                     f2bf(b.x), f2bf(b.y), f2bf(b.z), f2bf(b.w) };
        *(s16x8*)(dst + i) = *(const s16x8*)o;
    }
}

__global__ __launch_bounds__(256) void fill_sentinel(float* __restrict__ o, long n)
{
    const long stride = (long)gridDim.x * 256;
    for (long i = (long)blockIdx.x * 256 + threadIdx.x; i < n; i += stride)
        o[i] = 1.0f;   // sentinel: ws_size too small
}

// ---------------------------------------------------------------------------
// Fused transpose+convert: fp32 in [R][C] -> bf16 out [C][R]
// ---------------------------------------------------------------------------
__global__ __launch_bounds__(256) void transpose_f32_bf16(
    const float* __restrict__ in, u16* __restrict__ out, int R, int C)
{
    __shared__ u16 t[32][33];
    const int c0 = blockIdx.x * 32, r0 = blockIdx.y * 32;
    const int tx = threadIdx.x & 31, ty = threadIdx.x >> 5;
#pragma unroll
    for (int i = 0; i < 32; i += 8)
        t[ty + i][tx] = f2bf(in[(long)(r0 + ty + i) * C + c0 + tx]);
    __syncthreads();
#pragma unroll
    for (int i = 0; i < 32; i += 8)
        out[(long)(c0 + ty + i) * R + r0 + tx] = t[tx][ty + i];
}

// ---------------------------------------------------------------------------
// C[M][N] = A[M][K] @ BT[N][K]^T + bias[N]   (bf16 in, fp32 accum,
// fp32 bias). Output bf16 (FP32OUT=0) or fp32 (FP32OUT=1).
// 128x128 tile, BK=64, 4 waves (2x2 of 64x64), 16x16x32 MFMA.
// LDS staged via global_load_lds, source pre-swizzled (chunk ^= row&7).
// ---------------------------------------------------------------------------
template <int FP32OUT>
__global__ __launch_bounds__(256) void gemm_bt_bias(
    const u16* __restrict__ A, const u16* __restrict__ BT,
    const float* __restrict__ bias, void* __restrict__ Cout,
    int M, int N, int K)
{
    __shared__ u16 As[128 * 64];
    __shared__ u16 Bs[128 * 64];
    const int tid  = threadIdx.x;
    const int lane = tid & 63;
    const int wid  = tid >> 6;
    const int rr   = lane & 15, g = lane >> 4;
    const int wm   = (wid >> 1) << 6;
    const int wn   = (wid & 1) << 6;
    const long m0  = (long)blockIdx.y * 128;
    const long n0  = (long)blockIdx.x * 128;
    const int srow   = tid >> 3;               // 0..31
    const int schunk = (tid & 7) ^ (srow & 7); // pre-swizzled 16B-chunk index

    f32x4 acc[4][4] = {};

    for (int k0 = 0; k0 < K; k0 += 64) {
#pragma unroll
        for (int q = 0; q < 4; ++q) {
            const int row = q * 32 + srow;
            gload16(A  + (m0 + row) * K + k0 + schunk * 8,
                    (char*)As + q * 4096 + wid * 1024);
            gload16(BT + (n0 + row) * K + k0 + schunk * 8,
                    (char*)Bs + q * 4096 + wid * 1024);
        }
        __syncthreads();
#pragma unroll
        for (int kk = 0; kk < 2; ++kk) {
            s16x8 af[4], bfr[4];
#pragma unroll
            for (int i = 0; i < 4; ++i) {
                const int rowa = wm + i * 16 + rr;
                af[i] = *(const s16x8*)((const char*)As + rowa * 128 +
                         ((kk * 64 + g * 16) ^ ((rowa & 7) << 4)));
                const int rowb = wn + i * 16 + rr;
                bfr[i] = *(const s16x8*)((const char*)Bs + rowb * 128 +
                         ((kk * 64 + g * 16) ^ ((rowb & 7) << 4)));
            }
#pragma unroll
            for (int i = 0; i < 4; ++i)
#pragma unroll
                for (int j = 0; j < 4; ++j)
                    acc[i][j] = mfma16x16(af[i], bfr[j], acc[i][j]);
        }
        __syncthreads();
    }

#pragma unroll
    for (int j = 0; j < 4; ++j) {
        const long col = n0 + wn + j * 16 + rr;
        const float bv = bias[col];
#pragma unroll
        for (int i = 0; i < 4; ++i)
#pragma unroll
            for (int r = 0; r < 4; ++r) {
                const long rowg = m0 + wm + i * 16 + g * 4 + r;
                const float v = acc[i][j][r] + bv;
                if (FP32OUT) ((float*)Cout)[rowg * N + col] = v;
                else         ((u16*)Cout)[rowg * N + col] = f2bf(v);
            }
    }
}

// ---------------------------------------------------------------------------
// Factored attention: one wave per (b, h, p). Attention over NB=64 blocks.
// qkv row = b*8192 + n*128 + p, col = c*1024 + h*64 + d   (bf16)
// T = K @ Q^T (= S^T): both operands row-loads from global into registers.
// Softmax over m per column n (shfl_xor 16/32). P -> LDS (padded),
// V in LDS (swizzled), O = P@V.
// ---------------------------------------------------------------------------
__global__ __launch_bounds__(64) void attn_blocks(
    const u16* __restrict__ qkv, u16* __restrict__ o)
{
    __shared__ u16 Vlds[64 * 64];   // [k=64][d=64], rows XOR-swizzled by chunk
    __shared__ u16 Plds[64 * 72];   // [n=64][m=64 + pad 8]
    const int bid = blockIdx.x;
    const int b = bid >> 11;
    const int h = (bid >> 7) & 15;
    const int p = bid & 127;
    const int lane = threadIdx.x;
    const int rr = lane & 15, g = lane >> 4;
    const long NSTR = 128L * 3072;
    const long base = ((long)b * 8192 + p) * 3072 + h * 64;

    {   // stage V (c=2) into LDS, source pre-swizzled
        const int vrow = lane >> 3;
        const int vchunk = (lane & 7) ^ (vrow & 7);
#pragma unroll
        for (int q = 0; q < 8; ++q)
            gload16(qkv + base + (long)(q * 8 + vrow) * NSTR + 2048 + vchunk * 8,
                    (char*)Vlds + q * 1024);
    }

    s16x8 kf[4][2], qf[4][2];
#pragma unroll
    for (int t = 0; t < 4; ++t)
#pragma unroll
        for (int ks = 0; ks < 2; ++ks) {
            const long roff = base + (long)(t * 16 + rr) * NSTR + ks * 32 + g * 8;
            kf[t][ks] = *(const s16x8*)(qkv + roff + 1024);
            qf[t][ks] = *(const s16x8*)(qkv + roff);
        }

    f32x4 T[4][4] = {};
#pragma unroll
    for (int ks = 0; ks < 2; ++ks)
#pragma unroll
        for (int i = 0; i < 4; ++i)
#pragma unroll
            for (int jn = 0; jn < 4; ++jn)
                T[i][jn] = mfma16x16(kf[i][ks], qf[jn][ks], T[i][jn]);

    const float scale = 0.125f;
#pragma unroll
    for (int jn = 0; jn < 4; ++jn) {
        const int n = jn * 16 + rr;
        float pv[16];
        float mx = -3e38f;
#pragma unroll
        for (int i = 0; i < 4; ++i)
#pragma unroll
            for (int r = 0; r < 4; ++r) {
                const int m = i * 16 + g * 4 + r;
                const float s = (m <= n) ? T[i][jn][r] * scale : -3e38f;
                pv[i * 4 + r] = s;
                mx = fmaxf(mx, s);
            }
        mx = fmaxf(mx, __shfl_xor(mx, 16));
        mx = fmaxf(mx, __shfl_xor(mx, 32));
        float sum = 0.f;
#pragma unroll
        for (int t = 0; t < 16; ++t) {
            const float e = (pv[t] > -1e30f) ? __expf(pv[t] - mx) : 0.f;
            pv[t] = e;
            sum += e;
        }
        sum += __shfl_xor(sum, 16);
        sum += __shfl_xor(sum, 32);
        const float inv = 1.f / sum;
#pragma unroll
        for (int i = 0; i < 4; ++i)
#pragma unroll
            for (int rp = 0; rp < 2; ++rp) {
                const int m = i * 16 + g * 4 + rp * 2;
                const unsigned lo = f2bf(pv[i * 4 + rp * 2] * inv);
                const unsigned hi = f2bf(pv[i * 4 + rp * 2 + 1] * inv);
                *(unsigned*)((char*)Plds + n * 144 + m * 2) = lo | (hi << 16);
            }
    }

    wave_sync();   // drain V LDS-DMA (vmcnt) + P ds_writes (lgkmcnt)

    f32x4 O[4][4] = {};
#pragma unroll
    for (int ks = 0; ks < 2; ++ks) {
        s16x8 pa[4];
#pragma unroll
        for (int in = 0; in < 4; ++in)
            pa[in] = *(const s16x8*)((const char*)Plds +
                      (in * 16 + rr) * 144 + ks * 64 + g * 16);
#pragma unroll
        for (int jd = 0; jd < 4; ++jd) {
            s16x8 vb;
#pragma unroll
            for (int j = 0; j < 8; ++j) {
                const int k = ks * 32 + g * 8 + j;
                const int byte = (k * 128 + (jd * 16 + rr) * 2) ^ ((k & 7) << 4);
                vb[j] = *(const short*)((const char*)Vlds + byte);
            }
#pragma unroll
            for (int in = 0; in < 4; ++in)
                O[in][jd] = mfma16x16(pa[in], vb, O[in][jd]);
        }
    }

    const long obase = ((long)b * 8192 + p) * 1024 + h * 64;
#pragma unroll
    for (int in = 0; in < 4; ++in)
#pragma unroll
        for (int jd = 0; jd < 4; ++jd)
#pragma unroll
            for (int r = 0; r < 4; ++r) {
                const long n = in * 16 + g * 4 + r;
                const long d = jd * 16 + rr;
                o[obase + n * (128L * 1024) + d] = f2bf(O[in][jd][r]);
            }
}

// ---------------------------------------------------------------------------
extern "C" void kernel_launch(void* const* d_in, const int* in_sizes, int n_in,
                              void* d_out, int out_size, void* d_ws, size_t ws_size,
                              hipStream_t stream) {
    const float* x    = (const float*)d_in[0];   // (2, 8192, 1024) fp32
    const float* Wqkv = (const float*)d_in[1];   // (1024, 3072)
    const float* bq   = (const float*)d_in[2];   // (3072,)
    const float* Wout = (const float*)d_in[3];   // (1024, 1024)
    const float* bo   = (const float*)d_in[4];   // (1024,)

    char* ws = (char*)d_ws;
    u16* xb    = (u16*)(ws);                 // 33,554,432 B
    u16* qkv   = (u16*)(ws +  33554432L);    // 100,663,296 B
    u16* ob    = (u16*)(ws + 134217728L);    // 33,554,432 B
    u16* WqkvT = (u16*)(ws + 167772160L);    // 6,291,456 B
    u16* WoutT = (u16*)(ws + 174063616L);    // 2,097,152 B
    const size_t NEEDED = 176160768UL;

    if (ws_size < NEEDED) {   // diagnosable sentinel: all-1.0 output
        fill_sentinel<<<2048, 256, 0, stream>>>((float*)d_out, (long)out_size);
        return;
    }

    convert_x<<<2048, 256, 0, stream>>>(x, xb, 16777216L);
    transpose_f32_bf16<<<dim3(96, 32), 256, 0, stream>>>(Wqkv, WqkvT, 1024, 3072);
    transpose_f32_bf16<<<dim3(32, 32), 256, 0, stream>>>(Wout, WoutT, 1024, 1024);

    // qkv = x @ Wqkv + bqkv   (M=16384, N=3072, K=1024) -> bf16 ws
    gemm_bt_bias<0><<<dim3(24, 128), 256, 0, stream>>>(xb, WqkvT, bq, qkv,
                                                       16384, 3072, 1024);
    // factored attention over blocks
    attn_blocks<<<4096, 64, 0, stream>>>(qkv, ob);

    // out = o @ Wout + bout   (M=16384, N=1024, K=1024) -> fp32 d_out
    gemm_bt_bias<1><<<dim3(8, 128), 256, 0, stream>>>(ob, WoutT, bo, d_out,
                                                      16384, 1024, 1024);
}

// Round 5
// 224.017 us; speedup vs baseline: 9.2912x; 1.0744x over previous
//
#include <hip/hip_runtime.h>
#include <stdint.h>

typedef unsigned short u16;
typedef __attribute__((ext_vector_type(8))) short s16x8;   // 8 x bf16 (4 VGPRs)
typedef __attribute__((ext_vector_type(4))) float f32x4;   // MFMA accumulator

__device__ __forceinline__ f32x4 mfma16x16(s16x8 a, s16x8 b, f32x4 c) {
    return __builtin_amdgcn_mfma_f32_16x16x32_bf16(a, b, c, 0, 0, 0);
}

__device__ __forceinline__ u16 f2bf(float f) {
    union { float f; unsigned u; } c; c.f = f;
    unsigned u = c.u;
    return (u16)((u + 0x7FFFu + ((u >> 16) & 1u)) >> 16);   // RNE
}

// global -> LDS direct 16B load. LDS dest = wave-uniform base + lane*16.
__device__ __forceinline__ void gload16(const void* g, void* l) {
    auto gp = (const __attribute__((address_space(1))) unsigned int*)(g);
    auto lp = (__attribute__((address_space(3))) unsigned int*)(l);
    __builtin_amdgcn_global_load_lds(gp, lp, 16, 0, 0);
}

__device__ __forceinline__ void wave_sync() {
    __builtin_amdgcn_sched_barrier(0);
    asm volatile("s_waitcnt vmcnt(0) lgkmcnt(0)" ::: "memory");
    __builtin_amdgcn_sched_barrier(0);
    __builtin_amdgcn_s_barrier();
    __builtin_amdgcn_sched_barrier(0);
}

// ---------------------------------------------------------------------------
// x: fp32 -> bf16, vectorized, grid-stride. n % 8 == 0.
// ---------------------------------------------------------------------------
__global__ __launch_bounds__(256) void convert_x(
    const float* __restrict__ src, u16* __restrict__ dst, long n)
{
    const long stride = (long)gridDim.x * 256 * 8;
    for (long i = ((long)blockIdx.x * 256 + threadIdx.x) * 8; i < n; i += stride) {
        const float4 a = *(const float4*)(src + i);
        const float4 b = *(const float4*)(src + i + 4);
        u16 o[8] = { f2bf(a.x), f2bf(a.y), f2bf(a.z), f2bf(a.w),
                     f2bf(b.x), f2bf(b.y), f2bf(b.z), f2bf(b.w) };
        *(s16x8*)(dst + i) = *(const s16x8*)o;
    }
}

__global__ __launch_bounds__(256) void fill_sentinel(float* __restrict__ o, long n)
{
    const long stride = (long)gridDim.x * 256;
    for (long i = (long)blockIdx.x * 256 + threadIdx.x; i < n; i += stride)
        o[i] = 1.0f;   // sentinel: ws_size too small
}

// ---------------------------------------------------------------------------
// Fused transpose+convert: fp32 in [R][C] -> bf16 out [C][R]
// ---------------------------------------------------------------------------
__global__ __launch_bounds__(256) void transpose_f32_bf16(
    const float* __restrict__ in, u16* __restrict__ out, int R, int C)
{
    __shared__ u16 t[32][33];
    const int c0 = blockIdx.x * 32, r0 = blockIdx.y * 32;
    const int tx = threadIdx.x & 31, ty = threadIdx.x >> 5;
#pragma unroll
    for (int i = 0; i < 32; i += 8)
        t[ty + i][tx] = f2bf(in[(long)(r0 + ty + i) * C + c0 + tx]);
    __syncthreads();
#pragma unroll
    for (int i = 0; i < 32; i += 8)
        out[(long)(c0 + ty + i) * R + r0 + tx] = t[tx][ty + i];
}

// ---------------------------------------------------------------------------
// Deep-pipelined 256x256 GEMM: C = A @ BT^T + bias.  BK=32, 4 LDS buffers
// (128 KiB dynamic), prefetch 3 K-tiles ahead, counted vmcnt(8) per K-tile
// boundary, 2 phases x 16 MFMA per K-tile, setprio around MFMA clusters.
// 512 threads = 8 waves (2M x 4N), per-wave output 128x64.
// Buffer-liveness invariant: stage target (kt+3)&3 == (kt-1)&3, whose reads
// finished before the boundary barrier entering kt -> no write/read overlap.
// M must be 16384 (tm = g & 63). NT = K/32.
// ---------------------------------------------------------------------------
template <int FP32OUT, int NT>
__global__ __launch_bounds__(512, 2) void gemm256(
    const u16* __restrict__ A, const u16* __restrict__ BT,
    const float* __restrict__ bias, void* __restrict__ Cout,
    int N, int K)
{
    extern __shared__ char smem[];          // 131072 B: As 4x16KB | Bs 4x16KB
    char* const As = smem;
    char* const Bs = smem + 65536;

    const int tid  = threadIdx.x;
    const int lane = tid & 63;
    const int wid  = tid >> 6;
    const int rr   = lane & 15, g = lane >> 4;
    const int wr   = wid >> 2;        // 0..1  (M)
    const int wc   = wid & 3;         // 0..3  (N)

    // XCD-bijective swizzle (gridDim.x % 8 == 0), M-fastest for B-panel reuse
    const int nwg = gridDim.x;
    const int gsw = (blockIdx.x & 7) * (nwg >> 3) + (blockIdx.x >> 3);
    const long m0 = (long)(gsw & 63) * 256;
    const long n0 = (long)(gsw >> 6) * 256;

    // staging source (element offsets); swizzle: chunk ^= (row>>1)&3
    const int srow = tid >> 2;                       // 0..127
    const int cl   = (tid & 3) ^ ((tid >> 3) & 3);   // source 16B chunk
    const u16* pA0 = A  + (m0 + srow) * (long)K + cl * 8;
    const u16* pA1 = pA0 + 128 * (long)K;
    const u16* pB0 = BT + (n0 + srow) * (long)K + cl * 8;
    const u16* pB1 = pB0 + 128 * (long)K;
    const int sdst = wid * 1024;                     // wave-uniform LDS dest

    // fragment read bases (row*64 bytes + swizzled chunk)
    const int xg    = (g ^ ((rr >> 1) & 3)) << 4;
    const int abase = (wr * 128 + rr) * 64 + xg;     // + buf*16384 + m*1024
    const int bbase = (wc * 64  + rr) * 64 + xg;     // + buf*16384 + n*1024

    f32x4 acc[8][4] = {};

    // prologue: stage K-tiles 0,1,2 (12 loads/thread), wait oldest 4 (kt0)
#pragma unroll
    for (int t = 0; t < 3; ++t) {
        const long ko = (long)t * 32;
        const int  sb = t * 16384;
        gload16(pA0 + ko, As + sb + sdst);
        gload16(pA1 + ko, As + sb + 8192 + sdst);
        gload16(pB0 + ko, Bs + sb + sdst);
        gload16(pB1 + ko, Bs + sb + 8192 + sdst);
    }
    asm volatile("s_waitcnt vmcnt(8)" ::: "memory");
    __builtin_amdgcn_s_barrier();

    for (int kt = 0; kt < NT; ++kt) {
        const int  bb = (kt & 3) * 16384;
        const int  sb = ((kt + 3) & 3) * 16384;
        const long ko = (long)(kt + 3) * 32;
        const bool st = (kt + 3 < NT);

        // ---- phase A: stage A-half of kt+3; read B(all)+A(m0-3); 16 MFMA
        if (st) {
            gload16(pA0 + ko, As + sb + sdst);
            gload16(pA1 + ko, As + sb + 8192 + sdst);
        }
        s16x8 bf[4], af[4];
#pragma unroll
        for (int n = 0; n < 4; ++n)
            bf[n] = *(const s16x8*)(Bs + bb + bbase + n * 1024);
#pragma unroll
        for (int m = 0; m < 4; ++m)
            af[m] = *(const s16x8*)(As + bb + abase + m * 1024);
        asm volatile("s_waitcnt lgkmcnt(0)" ::: "memory");
        __builtin_amdgcn_sched_barrier(0);
        __builtin_amdgcn_s_setprio(1);
#pragma unroll
        for (int m = 0; m < 4; ++m)
#pragma unroll
            for (int n = 0; n < 4; ++n)
                acc[m][n] = mfma16x16(af[m], bf[n], acc[m][n]);
        __builtin_amdgcn_s_setprio(0);
        __builtin_amdgcn_s_barrier();

        // ---- phase B: stage B-half of kt+3; read A(m4-7); 16 MFMA
        if (st) {
            gload16(pB0 + ko, Bs + sb + sdst);
            gload16(pB1 + ko, Bs + sb + 8192 + sdst);
        }
#pragma unroll
        for (int m = 0; m < 4; ++m)
            af[m] = *(const s16x8*)(As + bb + abase + (m + 4) * 1024);
        asm volatile("s_waitcnt lgkmcnt(0)" ::: "memory");
        __builtin_amdgcn_sched_barrier(0);
        __builtin_amdgcn_s_setprio(1);
#pragma unroll
        for (int m = 0; m < 4; ++m)
#pragma unroll
            for (int n = 0; n < 4; ++n)
                acc[m + 4][n] = mfma16x16(af[m], bf[n], acc[m + 4][n]);
        __builtin_amdgcn_s_setprio(0);

        // ---- K-tile boundary: counted drain (kt+1 proven landed), barrier
        if (kt < NT - 3)       { asm volatile("s_waitcnt vmcnt(8)" ::: "memory"); }
        else if (kt == NT - 3) { asm volatile("s_waitcnt vmcnt(4)" ::: "memory"); }
        else if (kt == NT - 2) { asm volatile("s_waitcnt vmcnt(0)" ::: "memory"); }
        if (kt < NT - 1) __builtin_amdgcn_s_barrier();
    }

    // epilogue
#pragma unroll
    for (int n = 0; n < 4; ++n) {
        const long col = n0 + wc * 64 + n * 16 + rr;
        const float bv = bias[col];
#pragma unroll
        for (int m = 0; m < 8; ++m) {
            const long rb = m0 + wr * 128 + m * 16 + g * 4;
#pragma unroll
            for (int r = 0; r < 4; ++r) {
                const float v = acc[m][n][r] + bv;
                if (FP32OUT) ((float*)Cout)[(rb + r) * N + col] = v;
                else         ((u16*)Cout)[(rb + r) * N + col] = f2bf(v);
            }
        }
    }
}

// ---------------------------------------------------------------------------
// Fallback GEMM (proven R4 path): 128x128 tile, BK=64, 2-barrier loop.
// ---------------------------------------------------------------------------
template <int FP32OUT>
__global__ __launch_bounds__(256) void gemm_bt_bias(
    const u16* __restrict__ A, const u16* __restrict__ BT,
    const float* __restrict__ bias, void* __restrict__ Cout,
    int M, int N, int K)
{
    __shared__ u16 As[128 * 64];
    __shared__ u16 Bs[128 * 64];
    const int tid  = threadIdx.x;
    const int lane = tid & 63;
    const int wid  = tid >> 6;
    const int rr   = lane & 15, g = lane >> 4;
    const int wm   = (wid >> 1) << 6;
    const int wn   = (wid & 1) << 6;
    const long m0  = (long)blockIdx.y * 128;
    const long n0  = (long)blockIdx.x * 128;
    const int srow   = tid >> 3;
    const int schunk = (tid & 7) ^ (srow & 7);

    f32x4 acc[4][4] = {};

    for (int k0 = 0; k0 < K; k0 += 64) {
#pragma unroll
        for (int q = 0; q < 4; ++q) {
            const int row = q * 32 + srow;
            gload16(A  + (m0 + row) * K + k0 + schunk * 8,
                    (char*)As + q * 4096 + wid * 1024);
            gload16(BT + (n0 + row) * K + k0 + schunk * 8,
                    (char*)Bs + q * 4096 + wid * 1024);
        }
        __syncthreads();
#pragma unroll
        for (int kk = 0; kk < 2; ++kk) {
            s16x8 af[4], bfr[4];
#pragma unroll
            for (int i = 0; i < 4; ++i) {
                const int rowa = wm + i * 16 + rr;
                af[i] = *(const s16x8*)((const char*)As + rowa * 128 +
                         ((kk * 64 + g * 16) ^ ((rowa & 7) << 4)));
                const int rowb = wn + i * 16 + rr;
                bfr[i] = *(const s16x8*)((const char*)Bs + rowb * 128 +
                         ((kk * 64 + g * 16) ^ ((rowb & 7) << 4)));
            }
#pragma unroll
            for (int i = 0; i < 4; ++i)
#pragma unroll
                for (int j = 0; j < 4; ++j)
                    acc[i][j] = mfma16x16(af[i], bfr[j], acc[i][j]);
        }
        __syncthreads();
    }

#pragma unroll
    for (int j = 0; j < 4; ++j) {
        const long col = n0 + wn + j * 16 + rr;
        const float bv = bias[col];
#pragma unroll
        for (int i = 0; i < 4; ++i)
#pragma unroll
            for (int r = 0; r < 4; ++r) {
                const long rowg = m0 + wm + i * 16 + g * 4 + r;
                const float v = acc[i][j][r] + bv;
                if (FP32OUT) ((float*)Cout)[rowg * N + col] = v;
                else         ((u16*)Cout)[rowg * N + col] = f2bf(v);
            }
    }
}

// ---------------------------------------------------------------------------
// Factored attention: one wave per (b, h, p). Attention over NB=64 blocks.
// ---------------------------------------------------------------------------
__global__ __launch_bounds__(64) void attn_blocks(
    const u16* __restrict__ qkv, u16* __restrict__ o)
{
    __shared__ u16 Vlds[64 * 64];   // [k=64][d=64], rows XOR-swizzled by chunk
    __shared__ u16 Plds[64 * 72];   // [n=64][m=64 + pad 8]
    const int bid = blockIdx.x;
    const int b = bid >> 11;
    const int h = (bid >> 7) & 15;
    const int p = bid & 127;
    const int lane = threadIdx.x;
    const int rr = lane & 15, g = lane >> 4;
    const long NSTR = 128L * 3072;
    const long base = ((long)b * 8192 + p) * 3072 + h * 64;

    {   // stage V (c=2) into LDS, source pre-swizzled
        const int vrow = lane >> 3;
        const int vchunk = (lane & 7) ^ (vrow & 7);
#pragma unroll
        for (int q = 0; q < 8; ++q)
            gload16(qkv + base + (long)(q * 8 + vrow) * NSTR + 2048 + vchunk * 8,
                    (char*)Vlds + q * 1024);
    }

    s16x8 kf[4][2], qf[4][2];
#pragma unroll
    for (int t = 0; t < 4; ++t)
#pragma unroll
        for (int ks = 0; ks < 2; ++ks) {
            const long roff = base + (long)(t * 16 + rr) * NSTR + ks * 32 + g * 8;
            kf[t][ks] = *(const s16x8*)(qkv + roff + 1024);
            qf[t][ks] = *(const s16x8*)(qkv + roff);
        }

    f32x4 T[4][4] = {};
#pragma unroll
    for (int ks = 0; ks < 2; ++ks)
#pragma unroll
        for (int i = 0; i < 4; ++i)
#pragma unroll
            for (int jn = 0; jn < 4; ++jn)
                T[i][jn] = mfma16x16(kf[i][ks], qf[jn][ks], T[i][jn]);

    const float scale = 0.125f;
#pragma unroll
    for (int jn = 0; jn < 4; ++jn) {
        const int n = jn * 16 + rr;
        float pv[16];
        float mx = -3e38f;
#pragma unroll
        for (int i = 0; i < 4; ++i)
#pragma unroll
            for (int r = 0; r < 4; ++r) {
                const int m = i * 16 + g * 4 + r;
                const float s = (m <= n) ? T[i][jn][r] * scale : -3e38f;
                pv[i * 4 + r] = s;
                mx = fmaxf(mx, s);
            }
        mx = fmaxf(mx, __shfl_xor(mx, 16));
        mx = fmaxf(mx, __shfl_xor(mx, 32));
        float sum = 0.f;
#pragma unroll
        for (int t = 0; t < 16; ++t) {
            const float e = (pv[t] > -1e30f) ? __expf(pv[t] - mx) : 0.f;
            pv[t] = e;
            sum += e;
        }
        sum += __shfl_xor(sum, 16);
        sum += __shfl_xor(sum, 32);
        const float inv = 1.f / sum;
#pragma unroll
        for (int i = 0; i < 4; ++i)
#pragma unroll
            for (int rp = 0; rp < 2; ++rp) {
                const int m = i * 16 + g * 4 + rp * 2;
                const unsigned lo = f2bf(pv[i * 4 + rp * 2] * inv);
                const unsigned hi = f2bf(pv[i * 4 + rp * 2 + 1] * inv);
                *(unsigned*)((char*)Plds + n * 144 + m * 2) = lo | (hi << 16);
            }
    }

    wave_sync();   // drain V LDS-DMA (vmcnt) + P ds_writes (lgkmcnt)

    f32x4 O[4][4] = {};
#pragma unroll
    for (int ks = 0; ks < 2; ++ks) {
        s16x8 pa[4];
#pragma unroll
        for (int in = 0; in < 4; ++in)
            pa[in] = *(const s16x8*)((const char*)Plds +
                      (in * 16 + rr) * 144 + ks * 64 + g * 16);
#pragma unroll
        for (int jd = 0; jd < 4; ++jd) {
            s16x8 vb;
#pragma unroll
            for (int j = 0; j < 8; ++j) {
                const int k = ks * 32 + g * 8 + j;
                const int byte = (k * 128 + (jd * 16 + rr) * 2) ^ ((k & 7) << 4);
                vb[j] = *(const short*)((const char*)Vlds + byte);
            }
#pragma unroll
            for (int in = 0; in < 4; ++in)
                O[in][jd] = mfma16x16(pa[in], vb, O[in][jd]);
        }
    }

    const long obase = ((long)b * 8192 + p) * 1024 + h * 64;
#pragma unroll
    for (int in = 0; in < 4; ++in)
#pragma unroll
        for (int jd = 0; jd < 4; ++jd)
#pragma unroll
            for (int r = 0; r < 4; ++r) {
                const long n = in * 16 + g * 4 + r;
                const long d = jd * 16 + rr;
                o[obase + n * (128L * 1024) + d] = f2bf(O[in][jd][r]);
            }
}

// ---------------------------------------------------------------------------
extern "C" void kernel_launch(void* const* d_in, const int* in_sizes, int n_in,
                              void* d_out, int out_size, void* d_ws, size_t ws_size,
                              hipStream_t stream) {
    const float* x    = (const float*)d_in[0];   // (2, 8192, 1024) fp32
    const float* Wqkv = (const float*)d_in[1];   // (1024, 3072)
    const float* bq   = (const float*)d_in[2];   // (3072,)
    const float* Wout = (const float*)d_in[3];   // (1024, 1024)
    const float* bo   = (const float*)d_in[4];   // (1024,)

    char* ws = (char*)d_ws;
    u16* xb    = (u16*)(ws);                 // 33,554,432 B
    u16* qkv   = (u16*)(ws +  33554432L);    // 100,663,296 B
    u16* ob    = (u16*)(ws + 134217728L);    // 33,554,432 B
    u16* WqkvT = (u16*)(ws + 167772160L);    // 6,291,456 B
    u16* WoutT = (u16*)(ws + 174063616L);    // 2,097,152 B
    const size_t NEEDED = 176160768UL;

    if (ws_size < NEEDED) {   // diagnosable sentinel: all-1.0 output
        fill_sentinel<<<2048, 256, 0, stream>>>((float*)d_out, (long)out_size);
        return;
    }

    // opt in to 128 KiB dynamic LDS for the deep-pipelined GEMMs
    bool deep = true;
    if (hipFuncSetAttribute(reinterpret_cast<const void*>(&gemm256<0, 32>),
                            hipFuncAttributeMaxDynamicSharedMemorySize,
                            131072) != hipSuccess) deep = false;
    if (hipFuncSetAttribute(reinterpret_cast<const void*>(&gemm256<1, 32>),
                            hipFuncAttributeMaxDynamicSharedMemorySize,
                            131072) != hipSuccess) deep = false;

    convert_x<<<2048, 256, 0, stream>>>(x, xb, 16777216L);
    transpose_f32_bf16<<<dim3(96, 32), 256, 0, stream>>>(Wqkv, WqkvT, 1024, 3072);
    transpose_f32_bf16<<<dim3(32, 32), 256, 0, stream>>>(Wout, WoutT, 1024, 1024);

    // qkv = x @ Wqkv + bqkv   (M=16384, N=3072, K=1024) -> bf16 ws
    if (deep)
        gemm256<0, 32><<<768, 512, 131072, stream>>>(xb, WqkvT, bq, qkv,
                                                     3072, 1024);
    else
        gemm_bt_bias<0><<<dim3(24, 128), 256, 0, stream>>>(xb, WqkvT, bq, qkv,
                                                           16384, 3072, 1024);

    // factored attention over blocks
    attn_blocks<<<4096, 64, 0, stream>>>(qkv, ob);

    // out = o @ Wout + bout   (M=16384, N=1024, K=1024) -> fp32 d_out
    if (deep)
        gemm256<1, 32><<<256, 512, 131072, stream>>>(ob, WoutT, bo, d_out,
                                                     1024, 1024);
    else
        gemm_bt_bias<1><<<dim3(8, 128), 256, 0, stream>>>(ob, WoutT, bo, d_out,
                                                          16384, 1024, 1024);
}